// Round 1
// 1994.234 us; speedup vs baseline: 1.0311x; 1.0311x over previous
//
#include <hip/hip_runtime.h>
#include <cmath>

namespace {
constexpr int B_ = 16, T_ = 512, P_ = 256, E_ = 128, NB_ = 4, K_ = 4;
constexpr int THREADS_ = 512;

__device__ __forceinline__ float rcpf(float x) { return __builtin_amdgcn_rcpf(x); }
__device__ __forceinline__ float fast_tanh(float x) {
    float a = fabsf(x);
    float t = __expf(-2.0f * a);
    float r = 1.0f - 2.0f * t * rcpf(1.0f + t);
    return copysignf(r, x);
}
// sum over the 4 kq groups (lanes l, l^16, l^32, l^48)
__device__ __forceinline__ float redkq(float v) {
    v += __shfl_xor(v, 16);
    v += __shfl_xor(v, 32);
    return v;
}
// select a[kq] with compile-time indexing only (no scratch demotion)
__device__ __forceinline__ float sel4(int kq, float a, float b, float c, float d) {
    const float t0 = (kq & 1) ? b : a;
    const float t1 = (kq & 1) ? d : c;
    return (kq & 2) ? t1 : t0;
}
}

// R10: 512-thread / 8-wave layout (2 waves per SIMD for latency hiding).
// Lane (w,l): w = tid>>6 (0..7), sub = l&15, kq = l>>4 -> owns ONE element
//   e = (w<<4)|sub  (0..127), 4-way k-split per wave as before.
// Gather/scatter are b32; matvec reads padded s4 (stride 33 float4) so the
// 4 kq-group broadcast addresses hit distinct banks; sbuf padded to 36-float
// groups for the same reason. W_in hoisted to 8 registers/lane.
__global__ __launch_bounds__(512, 1)
void swarm_ring_kernel(const float* __restrict__ x,            // (B,T,8)
                       const float* __restrict__ W_in,         // (8,E)
                       const float* __restrict__ b_in,         // (E)
                       const float* __restrict__ W_out,        // (E,8)
                       const float* __restrict__ b_out,        // (8)
                       const float* __restrict__ W_p,          // (E,E)
                       const float* __restrict__ b_p,          // (E)
                       const float* __restrict__ ptr_dest,     // (NB,P)
                       const float* __restrict__ jump_W,       // (NB,E)
                       const float* __restrict__ jump_b,       // (NB)
                       const float* __restrict__ ctx_strength, // (NB)
                       const float* __restrict__ phase_bias,   // (NB,E)
                       const float* __restrict__ pointer_init, // (NB,B)
                       float* __restrict__ out)                // (B,T,8)
{
    __shared__ alignas(16) float  ring[P_ * E_];    // 128 KiB
    __shared__ alignas(16) float4 s4[132];          // fast: s1 of bots 0..3, padded (e + e/32)
    __shared__ alignas(16) float  sbuf[2][4][36];   // slow: s broadcast, padded groups
    __shared__ alignas(16) float  red[32];          // per-wave jump partials (float4 x 8)
    __shared__ alignas(16) float  hist[16][132];    // ssum history ring
    __shared__ alignas(16) float  wout_s[8][132];   // 0.25 * W_out^T

    const int tid = threadIdx.x;
    const int b   = blockIdx.x;
    const int w   = tid >> 6;
    const int l   = tid & 63;
    const int sub = l & 15;
    const int kq  = l >> 4;                         // 0..3
    const int e   = (w << 4) | sub;                 // owned element 0..127

    for (int k4 = tid; k4 < P_ * E_ / 4; k4 += THREADS_)
        ((float4*)ring)[k4] = make_float4(0.f, 0.f, 0.f, 0.f);
    for (int idx = tid; idx < 8 * E_; idx += THREADS_) {
        const int m = idx >> 7, ee = idx & 127;
        wout_s[m][ee] = W_out[ee * 8 + m] * 0.25f;
    }

    float wp[32];                                   // W_p[32*kq+kk][e]
    #pragma unroll
    for (int kk = 0; kk < 32; ++kk)
        wp[kk] = W_p[(kq * 32 + kk) * E_ + e];

    float wi[8];                                    // W_in[k][e] (hoisted)
    #pragma unroll
    for (int k = 0; k < 8; ++k)
        wi[k] = W_in[k * E_ + e];

    const float bin_r  = b_in[e];
    const float bp_r   = b_p[e];
    const float bout_m = b_out[tid & 7];

    float pb_r[NB_], jw_r[NB_], hid_r[NB_];
    float sigc[NB_], jb_r[NB_], ptrv[NB_];
    #pragma unroll
    for (int i = 0; i < NB_; ++i) {
        pb_r[i] = 0.1f * phase_bias[i * E_ + e];
        jw_r[i] = jump_W[i * E_ + e];
        sigc[i] = 1.0f / (1.0f + __expf(-ctx_strength[i]));
        jb_r[i] = jump_b[i];
        hid_r[i] = 0.f;
        ptrv[i] = pointer_init[i * B_ + b];
    }

    const float* xb = x + (size_t)b * T_ * 8;
    float xt[8];
    {
        float4 a0 = ((const float4*)xb)[0], a1 = ((const float4*)xb)[1];
        xt[0]=a0.x; xt[1]=a0.y; xt[2]=a0.z; xt[3]=a0.w;
        xt[4]=a1.x; xt[5]=a1.y; xt[6]=a1.z; xt[7]=a1.w;
    }

    const float Cw1 = 0.8824969f, Cw2 = 0.60653066f, Cw3 = 0.32465247f, Cw4 = 0.13533528f;
    const float Dw1 = 0.7788008f, Dw2 = 0.36787944f, Dw3 = 0.105399225f, Dw4 = 0.018315639f;

    __syncthreads();

    for (int t = 0; t < T_; ++t) {
        // ---- geometry, softmax weights, jump-target prefetch (proven math)
        int   baseA[NB_];
        float fA[NB_], psinv[NB_], jt[NB_], wgt[NB_][9];
        #pragma unroll
        for (int i = 0; i < NB_; ++i) {
            const float p = ptrv[i];
            const int base = (int)p;
            baseA[i] = base;
            jt[i] = ptr_dest[i * P_ + base];
            const float f = p - (float)base;
            fA[i] = f;
            const float r  = __expf(0.25f * f);
            const float r2 = r * r, r3 = r2 * r, r4 = r2 * r2;
            const float ri = rcpf(r), ri2 = ri * ri, ri3 = ri2 * ri, ri4 = ri2 * ri2;
            const float p0 = Cw4*ri4, p1 = Cw3*ri3, p2 = Cw2*ri2, p3 = Cw1*ri, p4 = 1.0f,
                        p5 = Cw1*r,  p6 = Cw2*r2,  p7 = Cw3*r3,  p8 = Cw4*r4;
            const float sum = ((p0+p1)+(p2+p3)) + ((p4+p5)+(p6+p7)) + p8;
            const float inv = rcpf(sum);
            psinv[i] = inv;
            wgt[i][0]=p0*inv; wgt[i][1]=p1*inv; wgt[i][2]=p2*inv; wgt[i][3]=p3*inv;
            wgt[i][4]=p4*inv; wgt[i][5]=p5*inv; wgt[i][6]=p6*inv; wgt[i][7]=p7*inv;
            wgt[i][8]=p8*inv;
        }

        // ---- block-uniform independence test
        int ddm[NB_][NB_];
        bool overlap = false;
        #pragma unroll
        for (int j = 1; j < NB_; ++j)
            #pragma unroll
            for (int i = 0; i < j; ++i) {
                const int dd = ((baseA[j] - baseA[i] + 128) & 255) - 128;
                ddm[j][i] = dd;
                overlap = overlap || (dd >= -8 && dd <= 8);
            }

        // ---- gathers: rows kq, kq+4 (+8 on kq0), b32; combine across kq
        float ws0[NB_], ws1[NB_];                   // selected weights (reused by scatter)
        float ctxp[NB_];
        #pragma unroll
        for (int i = 0; i < NB_; ++i) {
            ws0[i] = sel4(kq, wgt[i][0], wgt[i][1], wgt[i][2], wgt[i][3]);
            ws1[i] = sel4(kq, wgt[i][4], wgt[i][5], wgt[i][6], wgt[i][7]);
            const int r0 = (baseA[i] + kq - K_) & (P_ - 1);
            const int r1 = (baseA[i] + kq + 4 - K_) & (P_ - 1);
            const float g0 = ring[r0 * E_ + e];
            const float g1 = ring[r1 * E_ + e];
            float c = fmaf(ws1[i], g1, ws0[i] * g0);
            if (kq == 0) {
                const int r2 = (baseA[i] + 8 - K_) & (P_ - 1);
                c = fmaf(wgt[i][8], ring[r2 * E_ + e], c);
            }
            ctxp[i] = redkq(c);
        }

        // ---- inp = x_t @ W_in + b_in (W_in in registers)
        float inp = bin_r;
        #pragma unroll
        for (int k = 0; k < 8; ++k)
            inp = fmaf(xt[k], wi[k], inp);

        float xtn[8];
        if (t + 1 < T_) {
            float4 a0 = ((const float4*)(xb + (t + 1) * 8))[0];
            float4 a1 = ((const float4*)(xb + (t + 1) * 8))[1];
            xtn[0]=a0.x; xtn[1]=a0.y; xtn[2]=a0.z; xtn[3]=a0.w;
            xtn[4]=a1.x; xtn[5]=a1.y; xtn[6]=a1.z; xtn[7]=a1.w;
        } else {
            #pragma unroll
            for (int k = 0; k < 8; ++k) xtn[k] = 0.f;
        }

        float sv[NB_];

        if (!overlap) {
            // ================= FAST PATH: all 4 bots independent =================
            float s1v[NB_];
            #pragma unroll
            for (int j = 0; j < NB_; ++j)
                s1v[j] = fast_tanh(fmaf(sigc[j], ctxp[j], inp + pb_r[j] + hid_r[j]));
            if (kq == 0)
                s4[e + (e >> 5)] = make_float4(s1v[0], s1v[1], s1v[2], s1v[3]);
            __syncthreads();                        // ONE barrier for all 4 broadcasts

            float ab0 = 0.f, ab1 = 0.f, ab2 = 0.f, ab3 = 0.f;
            const float4* sp = s4 + kq * 33;
            #pragma unroll
            for (int kk = 0; kk < 32; ++kk) {
                const float4 sq = sp[kk];
                const float wk = wp[kk];
                ab0 = fmaf(sq.x, wk, ab0);
                ab1 = fmaf(sq.y, wk, ab1);
                ab2 = fmaf(sq.z, wk, ab2);
                ab3 = fmaf(sq.w, wk, ab3);
            }
            sv[0] = fast_tanh(redkq(ab0) + bp_r);
            sv[1] = fast_tanh(redkq(ab1) + bp_r);
            sv[2] = fast_tanh(redkq(ab2) + bp_r);
            sv[3] = fast_tanh(redkq(ab3) + bp_r);
            #pragma unroll
            for (int j = 0; j < NB_; ++j) hid_r[j] = sv[j];

            // disjoint b32 scatters: lane owns rows kq, kq+4 (+8 on kq0)
            #pragma unroll
            for (int j = 0; j < NB_; ++j) {
                const float s = sv[j];
                const int r0 = (baseA[j] + kq - K_) & (P_ - 1);
                ring[r0 * E_ + e] = fmaf(ws0[j], s, ring[r0 * E_ + e]);
                const int r1 = (baseA[j] + kq + 4 - K_) & (P_ - 1);
                ring[r1 * E_ + e] = fmaf(ws1[j], s, ring[r1 * E_ + e]);
                if (kq == 0) {
                    const int r2 = (baseA[j] + 8 - K_) & (P_ - 1);
                    ring[r2 * E_ + e] = fmaf(wgt[j][8], s, ring[r2 * E_ + e]);
                }
            }
        } else {
            // ================= SLOW PATH: serial chain with coef corrections =====
            float coefm[NB_][NB_];
            #pragma unroll
            for (int j = 1; j < NB_; ++j) {
                #pragma unroll
                for (int i = 0; i < j; ++i) {
                    const int dd = ddm[j][i];
                    float c = 0.f;
                    if (dd >= -8 && dd <= 8) {
                        const float A = (float)dd - fA[i];
                        const float s  = __expf(-0.25f * (A - fA[j]));
                        const float G  = __expf(0.125f * (fA[i] * fA[i] - A * A));
                        const float s2p = s * s, s3p = s2p * s, s4p = s2p * s2p;
                        const float si = rcpf(s), si2 = si * si, si3 = si2 * si, si4 = si2 * si2;
                        float acc = 0.f;
                        acc += (dd >= 0)              ? Dw4 * si4 : 0.f;
                        acc += (dd >= -1 && dd <= 7)  ? Dw3 * si3 : 0.f;
                        acc += (dd >= -2 && dd <= 6)  ? Dw2 * si2 : 0.f;
                        acc += (dd >= -3 && dd <= 5)  ? Dw1 * si  : 0.f;
                        acc += (dd >= -4 && dd <= 4)  ? 1.0f      : 0.f;
                        acc += (dd >= -5 && dd <= 3)  ? Dw1 * s   : 0.f;
                        acc += (dd >= -6 && dd <= 2)  ? Dw2 * s2p : 0.f;
                        acc += (dd >= -7 && dd <= 1)  ? Dw3 * s3p : 0.f;
                        acc += (dd <= 0)              ? Dw4 * s4p : 0.f;
                        c = psinv[i] * psinv[j] * G * acc;
                    }
                    coefm[j][i] = c;
                }
            }

            #pragma unroll
            for (int j = 0; j < NB_; ++j) {
                float ctx = ctxp[j];
                #pragma unroll
                for (int i = 0; i < j; ++i)
                    ctx = fmaf(coefm[j][i], sv[i], ctx);
                const float s1 = fast_tanh(fmaf(sigc[j], ctx, inp + pb_r[j] + hid_r[j]));
                if (kq == 0) sbuf[j & 1][e >> 5][e & 31] = s1;
                __syncthreads();                    // s broadcast ready

                const float4* sp4 = (const float4*)(sbuf[j & 1][kq]);
                float ax = 0.f;
                #pragma unroll
                for (int kk = 0; kk < 8; ++kk) {
                    const float4 sq = sp4[kk];
                    ax = fmaf(sq.x, wp[4 * kk + 0], ax);
                    ax = fmaf(sq.y, wp[4 * kk + 1], ax);
                    ax = fmaf(sq.z, wp[4 * kk + 2], ax);
                    ax = fmaf(sq.w, wp[4 * kk + 3], ax);
                }
                const float s2 = fast_tanh(redkq(ax) + bp_r);
                sv[j] = s2; hid_r[j] = s2;

                const int r0 = (baseA[j] + kq - K_) & (P_ - 1);
                ring[r0 * E_ + e] = fmaf(ws0[j], s2, ring[r0 * E_ + e]);
                const int r1 = (baseA[j] + kq + 4 - K_) & (P_ - 1);
                ring[r1 * E_ + e] = fmaf(ws1[j], s2, ring[r1 * E_ + e]);
                if (kq == 0) {
                    const int r2 = (baseA[j] + 8 - K_) & (P_ - 1);
                    ring[r2 * E_ + e] = fmaf(wgt[j][8], s2, ring[r2 * E_ + e]);
                }
            }
        }

        // ---- jump dots: per-lane element product, reduce over the 16 subs
        {
            float vj0 = sv[0] * jw_r[0];
            float vj1 = sv[1] * jw_r[1];
            float vj2 = sv[2] * jw_r[2];
            float vj3 = sv[3] * jw_r[3];
            #pragma unroll
            for (int off = 1; off < 16; off <<= 1) {
                vj0 += __shfl_xor(vj0, off);
                vj1 += __shfl_xor(vj1, off);
                vj2 += __shfl_xor(vj2, off);
                vj3 += __shfl_xor(vj3, off);
            }
            if (l == 0)
                ((float4*)red)[w] = make_float4(vj0, vj1, vj2, vj3);
        }

        // ---- ssum -> history ring (kq0 lanes, b32)
        {
            const float ssum = (sv[0] + sv[1]) + (sv[2] + sv[3]);
            if (kq == 0) hist[t & 15][e] = ssum;
        }

        __syncthreads();                            // scatters + red + hist visible

        {
            const float4 r0 = ((const float4*)red)[0];
            const float4 r1 = ((const float4*)red)[1];
            const float4 r2 = ((const float4*)red)[2];
            const float4 r3 = ((const float4*)red)[3];
            const float4 r4 = ((const float4*)red)[4];
            const float4 r5 = ((const float4*)red)[5];
            const float4 r6 = ((const float4*)red)[6];
            const float4 r7 = ((const float4*)red)[7];
            const float zz[4] = {
                (((r0.x + r1.x) + (r2.x + r3.x)) + ((r4.x + r5.x) + (r6.x + r7.x))) + jb_r[0],
                (((r0.y + r1.y) + (r2.y + r3.y)) + ((r4.y + r5.y) + (r6.y + r7.y))) + jb_r[1],
                (((r0.z + r1.z) + (r2.z + r3.z)) + ((r4.z + r5.z) + (r6.z + r7.z))) + jb_r[2],
                (((r0.w + r1.w) + (r2.w + r3.w)) + ((r4.w + r5.w) + (r6.w + r7.w))) + jb_r[3]};
            #pragma unroll
            for (int i = 0; i < NB_; ++i) {
                float np;
                if (zz[i] > 0.0f) np = jt[i];
                else { np = ptrv[i] + 1.0f; if (np >= 256.0f) np -= 256.0f; }
                ptrv[i] = np;
            }
        }

        // ---- every 8th step: 64 threads compute the deferred out dots
        if ((t & 7) == 7 && tid < 64) {
            const int tt = tid >> 3;
            const int m  = tid & 7;
            const float* hrow = hist[(t - 7 + tt) & 15];
            const float* wrow = wout_s[m];
            float acc = 0.f;
            #pragma unroll
            for (int q = 0; q < 32; ++q) {
                const float4 h4 = ((const float4*)hrow)[q];
                const float4 w4 = ((const float4*)wrow)[q];
                acc += ((h4.x * w4.x + h4.y * w4.y) + (h4.z * w4.z + h4.w * w4.w));
            }
            out[((size_t)b * T_ + (t - 7 + tt)) * 8 + m] = acc + bout_m;
        }

        #pragma unroll
        for (int k = 0; k < 8; ++k) xt[k] = xtn[k];
    }
}

extern "C" void kernel_launch(void* const* d_in, const int* in_sizes, int n_in,
                              void* d_out, int out_size, void* d_ws, size_t ws_size,
                              hipStream_t stream) {
    (void)in_sizes; (void)n_in; (void)out_size; (void)d_ws; (void)ws_size;
    swarm_ring_kernel<<<dim3(B_), dim3(THREADS_), 0, stream>>>(
        (const float*)d_in[0],  (const float*)d_in[1],  (const float*)d_in[2],
        (const float*)d_in[3],  (const float*)d_in[4],  (const float*)d_in[5],
        (const float*)d_in[6],  (const float*)d_in[7],  (const float*)d_in[8],
        (const float*)d_in[9],  (const float*)d_in[10], (const float*)d_in[11],
        (const float*)d_in[12], (float*)d_out);
}